// Round 3
// baseline (199.123 us; speedup 1.0000x reference)
//
#include <hip/hip_runtime.h>
#include <math.h>

// GCN 2-layer, algebraically fused:
//   agg_x[d] = dinv[d]*(sum_{s in N(d)} xp[s] + xp[d]),  xp = dinv*x
//   h = relu(agg_x@W1+b1); g = h@W2; gp = dinv*g
//   out = log_softmax(dinv[d]*(sum gp[s] + gp[d]) + b2)
//
// R11 (157.1us): counting sort -> node-contiguous records, atomic-free
// segmented sums, MLP fused into agg1.
// R12 (315us): global-atomic degree -> 100MB cross-XCD write traffic. Bad.
// R13 (190.7us): sort-free LDS-atomic agg + k_deg histogram pass. agg1/agg2
//   = 47us each, latency-bound: VGPR=12/20 shows the compiler serialized the
//   random xp/gp gathers into load->wait->atomic chains (~2 loads in flight).
// R14: de-serialize the bucket-pass kernels. Branch-free guards (invalid
//   slots -> dummy acc slot 256 / gather idx 0), 2-quad batching (8 gathers
//   in flight per thread), sched_barrier(0) between gather group and atomic
//   group so one pipelined waitcnt covers all loads. `sorted` padded +4352
//   entries so pair-loads never go OOB. k_scatter: issue 4 pos-atomics
//   before stores.
// Fixed ~43us of the measured total is harness workspace fill.

#define BLK 256
#define NTILE 512
#define EPTMAX 6400        // >= runtime ept (6252), multiple of 4
#define MAXB 512           // >= nbkt = 391
#define MSK 0x1FFFFu

// ---------- Phase A ----------

__global__ void k_hist(const int* __restrict__ dst, int* __restrict__ table,
                       int e, int ept, int nbkt) {
    __shared__ int h[MAXB];
    int tile = blockIdx.x;
    for (int i = threadIdx.x; i < MAXB; i += BLK) h[i] = 0;
    __syncthreads();
    int lo = tile * ept;
    int hi = min(lo + ept, e);
    for (int i = lo + 4 * threadIdx.x; i < hi; i += 4 * BLK) {
        int4 d4 = *(const int4*)(dst + i);
        atomicAdd(&h[d4.x >> 8], 1);
        atomicAdd(&h[d4.y >> 8], 1);
        atomicAdd(&h[d4.z >> 8], 1);
        atomicAdd(&h[d4.w >> 8], 1);
    }
    __syncthreads();
    for (int i = threadIdx.x; i < nbkt; i += BLK)
        table[tile * nbkt + i] = h[i];
}

__global__ void k_scan_col(int* __restrict__ table, int* __restrict__ tot, int nbkt) {
    __shared__ int wsum[NTILE / 64];
    int b = blockIdx.x;
    int t = threadIdx.x;
    int v = table[t * nbkt + b];
    int x = v;
    int lane = t & 63;
#pragma unroll
    for (int ofs = 1; ofs < 64; ofs <<= 1) {
        int y = __shfl_up(x, ofs, 64);
        if (lane >= ofs) x += y;
    }
    if (lane == 63) wsum[t >> 6] = x;
    __syncthreads();
    if (t < NTILE / 64) {
        int s = wsum[t];
        int w = s;
#pragma unroll
        for (int ofs = 1; ofs < NTILE / 64; ofs <<= 1) {
            int y = __shfl_up(w, ofs, 64);
            if (t >= ofs) w += y;
        }
        wsum[t] = w - s;
    }
    __syncthreads();
    int incl = x + wsum[t >> 6];
    table[t * nbkt + b] = incl - v;
    if (t == NTILE - 1) tot[b] = incl;
}

__global__ void k_scan_tot(const int* __restrict__ tot, int* __restrict__ bkt_off, int nbkt) {
    __shared__ int wsum[MAXB / 64];
    int t = threadIdx.x;               // MAXB threads
    int v = (t < nbkt) ? tot[t] : 0;
    int x = v;
    int lane = t & 63;
#pragma unroll
    for (int ofs = 1; ofs < 64; ofs <<= 1) {
        int y = __shfl_up(x, ofs, 64);
        if (lane >= ofs) x += y;
    }
    if (lane == 63) wsum[t >> 6] = x;
    __syncthreads();
    if (t < MAXB / 64) {
        int s = wsum[t];
        int w = s;
#pragma unroll
        for (int ofs = 1; ofs < MAXB / 64; ofs <<= 1) {
            int y = __shfl_up(w, ofs, 64);
            if (t >= ofs) w += y;
        }
        wsum[t] = w - s;
    }
    __syncthreads();
    int incl = x + wsum[t >> 6];
    if (t < nbkt) bkt_off[t] = incl - v;
    if (t == nbkt - 1) bkt_off[nbkt] = incl;
}

__global__ void k_scatter(const int* __restrict__ src, const int* __restrict__ dst,
                          const int* __restrict__ table, const int* __restrict__ tot,
                          const int* __restrict__ bkt_off, unsigned* __restrict__ sorted,
                          int e, int ept, int nbkt) {
    __shared__ int cur[MAXB];
    __shared__ int base2[MAXB];
    __shared__ unsigned stage[EPTMAX];
    __shared__ unsigned short stage_b[EPTMAX];
    __shared__ int wpart[BLK / 64];
    int tile = blockIdx.x;
    int t = threadIdx.x;
    int lo = tile * ept;
    int hi = min(lo + ept, e);
    int total = hi - lo;

    int b0 = 2 * t, b1 = 2 * t + 1;
    int c0 = 0, c1 = 0, g0 = 0, g1 = 0;
    if (b0 < nbkt) {
        int base = table[tile * nbkt + b0];
        int next = (tile < NTILE - 1) ? table[(tile + 1) * nbkt + b0] : tot[b0];
        c0 = next - base;
        g0 = bkt_off[b0] + base;
    }
    if (b1 < nbkt) {
        int base = table[tile * nbkt + b1];
        int next = (tile < NTILE - 1) ? table[(tile + 1) * nbkt + b1] : tot[b1];
        c1 = next - base;
        g1 = bkt_off[b1] + base;
    }
    int p = c0 + c1;
    int x = p;
    int lane = t & 63;
#pragma unroll
    for (int ofs = 1; ofs < 64; ofs <<= 1) {
        int y = __shfl_up(x, ofs, 64);
        if (lane >= ofs) x += y;
    }
    if (lane == 63) wpart[t >> 6] = x;
    __syncthreads();
    if (t < BLK / 64) {
        int s = wpart[t];
        int w = s;
#pragma unroll
        for (int ofs = 1; ofs < BLK / 64; ofs <<= 1) {
            int y = __shfl_up(w, ofs, 64);
            if (t >= ofs) w += y;
        }
        wpart[t] = w - s;
    }
    __syncthreads();
    int E = x + wpart[t >> 6] - p;
    cur[b0] = E;
    cur[b1] = E + c0;
    if (b0 < nbkt) base2[b0] = g0 - E;
    if (b1 < nbkt) base2[b1] = g1 - (E + c0);
    __syncthreads();

    for (int i = lo + 4 * t; i < hi; i += 4 * BLK) {
        int4 s4 = *(const int4*)(src + i);
        int4 d4 = *(const int4*)(dst + i);
        int q0 = d4.x >> 8, q1 = d4.y >> 8, q2 = d4.z >> 8, q3 = d4.w >> 8;
        int p0 = atomicAdd(&cur[q0], 1);
        int p1 = atomicAdd(&cur[q1], 1);
        int p2 = atomicAdd(&cur[q2], 1);
        int p3 = atomicAdd(&cur[q3], 1);
        stage[p0] = (unsigned)s4.x | ((unsigned)(d4.x & 255) << 17); stage_b[p0] = (unsigned short)q0;
        stage[p1] = (unsigned)s4.y | ((unsigned)(d4.y & 255) << 17); stage_b[p1] = (unsigned short)q1;
        stage[p2] = (unsigned)s4.z | ((unsigned)(d4.z & 255) << 17); stage_b[p2] = (unsigned short)q2;
        stage[p3] = (unsigned)s4.w | ((unsigned)(d4.w & 255) << 17); stage_b[p3] = (unsigned short)q3;
    }
    __syncthreads();
    for (int j = t; j < total; j += BLK) {
        int b = stage_b[j];
        sorted[base2[b] + j] = stage[j];
    }
}

// ---------- degree via per-bucket LDS histogram (branch-free, batched) ----------
__global__ __launch_bounds__(1024) void k_deg(
        const unsigned* __restrict__ sorted, const int* __restrict__ bkt_off,
        const float* __restrict__ x, float* __restrict__ dinv,
        float* __restrict__ xp, int n) {
    __shared__ int cnt[272];                // slot 256 = dummy
    int b = blockIdx.x, t = threadIdx.x;
    if (t < 272) cnt[t] = 0;
    __syncthreads();
    int lo = bkt_off[b], hi = bkt_off[b + 1];
    int la = lo & ~3;
    for (int i = la + 4 * t; i < hi; i += 8192) {
        int j = i + 4096;
        uint4 ra = *(const uint4*)(sorted + i);   // pad covers overread
        uint4 rb = *(const uint4*)(sorted + j);
        int d0 = (i + 0 >= lo && i + 0 < hi) ? (int)(ra.x >> 17) : 256;
        int d1 = (i + 1 >= lo && i + 1 < hi) ? (int)(ra.y >> 17) : 256;
        int d2 = (i + 2 >= lo && i + 2 < hi) ? (int)(ra.z >> 17) : 256;
        int d3 = (i + 3 >= lo && i + 3 < hi) ? (int)(ra.w >> 17) : 256;
        int d4 = (j + 0 < hi) ? (int)(rb.x >> 17) : 256;
        int d5 = (j + 1 < hi) ? (int)(rb.y >> 17) : 256;
        int d6 = (j + 2 < hi) ? (int)(rb.z >> 17) : 256;
        int d7 = (j + 3 < hi) ? (int)(rb.w >> 17) : 256;
        __builtin_amdgcn_sched_barrier(0);
        atomicAdd(&cnt[d0], 1);
        atomicAdd(&cnt[d1], 1);
        atomicAdd(&cnt[d2], 1);
        atomicAdd(&cnt[d3], 1);
        atomicAdd(&cnt[d4], 1);
        atomicAdd(&cnt[d5], 1);
        atomicAdd(&cnt[d6], 1);
        atomicAdd(&cnt[d7], 1);
    }
    __syncthreads();
    int node = (b << 8) + t;
    if (t < 256 && node < n) {
        float d = rsqrtf((float)cnt[t] + 1.0f);   // +1 self loop
        dinv[node] = d;
        float2 xv = ((const float2*)x)[node];
        ((float2*)xp)[node] = make_float2(d * xv.x, d * xv.y);
    }
}

// ---------- Phase B: bucket-local LDS float-atomic aggregation ----------
// One block per bucket (256 consecutive nodes). Records are bucket-
// contiguous in `sorted`; no intra-bucket order needed for a sum.
// Branch-free guards + 2-quad batching keep 8 gathers in flight.

// layer 1 + fused MLP: gp[d] = dinv[d]*(relu(aggx@W1+b1)@W2)
__global__ __launch_bounds__(1024) void k_agg1(
        const unsigned* __restrict__ sorted, const int* __restrict__ bkt_off,
        const float* __restrict__ xp, const float* __restrict__ dinv,
        const float* __restrict__ W1, const float* __restrict__ b1,
        const float* __restrict__ W2, float* __restrict__ gp, int n) {
    __shared__ float accx[272];             // slot 256 = dummy
    __shared__ float accy[272];
    int b = blockIdx.x, t = threadIdx.x;
    if (t < 272) { accx[t] = 0.f; accy[t] = 0.f; }
    __syncthreads();
    int lo = bkt_off[b], hi = bkt_off[b + 1];
    int la = lo & ~3;
    const float2* xp2 = (const float2*)xp;
    for (int i = la + 4 * t; i < hi; i += 8192) {
        int j = i + 4096;
        uint4 ra = *(const uint4*)(sorted + i);   // pad covers overread
        uint4 rb = *(const uint4*)(sorted + j);
        bool a0 = (i + 0 >= lo) && (i + 0 < hi);
        bool a1 = (i + 1 >= lo) && (i + 1 < hi);
        bool a2 = (i + 2 >= lo) && (i + 2 < hi);
        bool a3 = (i + 3 >= lo) && (i + 3 < hi);
        bool c0 = (j + 0 < hi);
        bool c1 = (j + 1 < hi);
        bool c2 = (j + 2 < hi);
        bool c3 = (j + 3 < hi);
        unsigned s0 = a0 ? (ra.x & MSK) : 0u;  int e0 = a0 ? (int)(ra.x >> 17) : 256;
        unsigned s1 = a1 ? (ra.y & MSK) : 0u;  int e1 = a1 ? (int)(ra.y >> 17) : 256;
        unsigned s2 = a2 ? (ra.z & MSK) : 0u;  int e2 = a2 ? (int)(ra.z >> 17) : 256;
        unsigned s3 = a3 ? (ra.w & MSK) : 0u;  int e3 = a3 ? (int)(ra.w >> 17) : 256;
        unsigned s4 = c0 ? (rb.x & MSK) : 0u;  int e4 = c0 ? (int)(rb.x >> 17) : 256;
        unsigned s5 = c1 ? (rb.y & MSK) : 0u;  int e5 = c1 ? (int)(rb.y >> 17) : 256;
        unsigned s6 = c2 ? (rb.z & MSK) : 0u;  int e6 = c2 ? (int)(rb.z >> 17) : 256;
        unsigned s7 = c3 ? (rb.w & MSK) : 0u;  int e7 = c3 ? (int)(rb.w >> 17) : 256;
        float2 f0 = xp2[s0];
        float2 f1 = xp2[s1];
        float2 f2 = xp2[s2];
        float2 f3 = xp2[s3];
        float2 f4 = xp2[s4];
        float2 f5 = xp2[s5];
        float2 f6 = xp2[s6];
        float2 f7 = xp2[s7];
        __builtin_amdgcn_sched_barrier(0);
        atomicAdd(&accx[e0], f0.x); atomicAdd(&accy[e0], f0.y);
        atomicAdd(&accx[e1], f1.x); atomicAdd(&accy[e1], f1.y);
        atomicAdd(&accx[e2], f2.x); atomicAdd(&accy[e2], f2.y);
        atomicAdd(&accx[e3], f3.x); atomicAdd(&accy[e3], f3.y);
        atomicAdd(&accx[e4], f4.x); atomicAdd(&accy[e4], f4.y);
        atomicAdd(&accx[e5], f5.x); atomicAdd(&accy[e5], f5.y);
        atomicAdd(&accx[e6], f6.x); atomicAdd(&accy[e6], f6.y);
        atomicAdd(&accx[e7], f7.x); atomicAdd(&accy[e7], f7.y);
    }
    __syncthreads();
    int nd = (b << 8) + t;
    if (t < 256 && nd < n) {
        float d = dinv[nd];
        float2 xv = xp2[nd];
        float ax = d * (accx[t] + xv.x), ay = d * (accy[t] + xv.y);
        float g0 = 0.f, g1 = 0.f;
#pragma unroll
        for (int f = 0; f < 16; ++f) {
            float h = fmaf(ax, W1[f], fmaf(ay, W1[16 + f], b1[f]));
            h = fmaxf(h, 0.0f);
            g0 = fmaf(h, W2[2 * f + 0], g0);
            g1 = fmaf(h, W2[2 * f + 1], g1);
        }
        ((float2*)gp)[nd] = make_float2(d * g0, d * g1);
    }
}

// layer 2 + bias + log_softmax
__global__ __launch_bounds__(1024) void k_agg2(
        const unsigned* __restrict__ sorted, const int* __restrict__ bkt_off,
        const float* __restrict__ gp, const float* __restrict__ dinv,
        const float* __restrict__ b2, float* __restrict__ out, int n) {
    __shared__ float accx[272];             // slot 256 = dummy
    __shared__ float accy[272];
    int b = blockIdx.x, t = threadIdx.x;
    if (t < 272) { accx[t] = 0.f; accy[t] = 0.f; }
    __syncthreads();
    int lo = bkt_off[b], hi = bkt_off[b + 1];
    int la = lo & ~3;
    const float2* gp2 = (const float2*)gp;
    for (int i = la + 4 * t; i < hi; i += 8192) {
        int j = i + 4096;
        uint4 ra = *(const uint4*)(sorted + i);
        uint4 rb = *(const uint4*)(sorted + j);
        bool a0 = (i + 0 >= lo) && (i + 0 < hi);
        bool a1 = (i + 1 >= lo) && (i + 1 < hi);
        bool a2 = (i + 2 >= lo) && (i + 2 < hi);
        bool a3 = (i + 3 >= lo) && (i + 3 < hi);
        bool c0 = (j + 0 < hi);
        bool c1 = (j + 1 < hi);
        bool c2 = (j + 2 < hi);
        bool c3 = (j + 3 < hi);
        unsigned s0 = a0 ? (ra.x & MSK) : 0u;  int e0 = a0 ? (int)(ra.x >> 17) : 256;
        unsigned s1 = a1 ? (ra.y & MSK) : 0u;  int e1 = a1 ? (int)(ra.y >> 17) : 256;
        unsigned s2 = a2 ? (ra.z & MSK) : 0u;  int e2 = a2 ? (int)(ra.z >> 17) : 256;
        unsigned s3 = a3 ? (ra.w & MSK) : 0u;  int e3 = a3 ? (int)(ra.w >> 17) : 256;
        unsigned s4 = c0 ? (rb.x & MSK) : 0u;  int e4 = c0 ? (int)(rb.x >> 17) : 256;
        unsigned s5 = c1 ? (rb.y & MSK) : 0u;  int e5 = c1 ? (int)(rb.y >> 17) : 256;
        unsigned s6 = c2 ? (rb.z & MSK) : 0u;  int e6 = c2 ? (int)(rb.z >> 17) : 256;
        unsigned s7 = c3 ? (rb.w & MSK) : 0u;  int e7 = c3 ? (int)(rb.w >> 17) : 256;
        float2 f0 = gp2[s0];
        float2 f1 = gp2[s1];
        float2 f2 = gp2[s2];
        float2 f3 = gp2[s3];
        float2 f4 = gp2[s4];
        float2 f5 = gp2[s5];
        float2 f6 = gp2[s6];
        float2 f7 = gp2[s7];
        __builtin_amdgcn_sched_barrier(0);
        atomicAdd(&accx[e0], f0.x); atomicAdd(&accy[e0], f0.y);
        atomicAdd(&accx[e1], f1.x); atomicAdd(&accy[e1], f1.y);
        atomicAdd(&accx[e2], f2.x); atomicAdd(&accy[e2], f2.y);
        atomicAdd(&accx[e3], f3.x); atomicAdd(&accy[e3], f3.y);
        atomicAdd(&accx[e4], f4.x); atomicAdd(&accy[e4], f4.y);
        atomicAdd(&accx[e5], f5.x); atomicAdd(&accy[e5], f5.y);
        atomicAdd(&accx[e6], f6.x); atomicAdd(&accy[e6], f6.y);
        atomicAdd(&accx[e7], f7.x); atomicAdd(&accy[e7], f7.y);
    }
    __syncthreads();
    int nd = (b << 8) + t;
    if (t < 256 && nd < n) {
        float d = dinv[nd];
        float2 gv = gp2[nd];
        float z0 = d * (accx[t] + gv.x) + b2[0];
        float z1 = d * (accy[t] + gv.y) + b2[1];
        float m = fmaxf(z0, z1);
        float lse = m + logf(expf(z0 - m) + expf(z1 - m));
        ((float2*)out)[nd] = make_float2(z0 - lse, z1 - lse);
    }
}

extern "C" void kernel_launch(void* const* d_in, const int* in_sizes, int n_in,
                              void* d_out, int out_size, void* d_ws, size_t ws_size,
                              hipStream_t stream) {
    const float* x  = (const float*)d_in[0];   // [n,2]
    const int*   ei = (const int*)d_in[1];     // [2,e]: row0=src, row1=dst
    const float* W1 = (const float*)d_in[2];   // [2,16]
    const float* b1 = (const float*)d_in[3];   // [16]
    const float* W2 = (const float*)d_in[4];   // [16,2]
    const float* b2 = (const float*)d_in[5];   // [2]
    float* out = (float*)d_out;                // [n,2]

    const int n = in_sizes[0] / 2;             // 100000
    const int e = in_sizes[1] / 2;             // 3200000
    const int* src = ei;
    const int* dst = ei + e;

    const int nbkt = (n + 255) >> 8;           // 391
    int ept = (((e + NTILE - 1) / NTILE) + 3) & ~3;   // 6252

    char* base = (char*)d_ws;
    size_t off = 0;
    auto take = [&](size_t bytes) { char* p = base + off; off += (bytes + 255) & ~(size_t)255; return p; };
    unsigned* sorted  = (unsigned*)take(((size_t)e + 4352) * 4);          // 12.8 MB + pair-load pad
    int*      table   = (int*)take((size_t)NTILE * nbkt * 4);             // 0.8 MB
    int*      tot     = (int*)take((size_t)MAXB * 4);
    int*      bkt_off = (int*)take((size_t)(MAXB + 1) * 4);
    float*    dinv    = (float*)take((size_t)n * 4);
    float*    xp      = (float*)take((size_t)n * 8);
    float*    gp      = (float*)take((size_t)n * 8);

    k_hist    <<<NTILE, BLK, 0, stream>>>(dst, table, e, ept, nbkt);
    k_scan_col<<<nbkt, NTILE, 0, stream>>>(table, tot, nbkt);
    k_scan_tot<<<1, MAXB, 0, stream>>>(tot, bkt_off, nbkt);
    k_scatter <<<NTILE, BLK, 0, stream>>>(src, dst, table, tot, bkt_off, sorted, e, ept, nbkt);
    k_deg     <<<nbkt, 1024, 0, stream>>>(sorted, bkt_off, x, dinv, xp, n);
    k_agg1    <<<nbkt, 1024, 0, stream>>>(sorted, bkt_off, xp, dinv, W1, b1, W2, gp, n);
    k_agg2    <<<nbkt, 1024, 0, stream>>>(sorted, bkt_off, gp, dinv, b2, out, n);
}

// Round 4
// 157.342 us; speedup vs baseline: 1.2655x; 1.2655x over previous
//
#include <hip/hip_runtime.h>
#include <math.h>

// GCN 2-layer, algebraically fused:
//   agg_x[d] = dinv[d]*(sum_{s in N(d)} xp[s] + xp[d]),  xp = dinv*x
//   h = relu(agg_x@W1+b1); g = h@W2; gp = dinv*g
//   out = log_softmax(dinv[d]*(sum gp[s] + gp[d]) + b2)
//
// R11 (157.1us, BEST): two-level counting sort -> node-contiguous records;
//   atomic-free segmented-sum aggregation (4 lanes/node, shfl quad reduce);
//   MLP fused into k_agg1 epilogue. ~43us of total is harness fill.
// R12-R14 (315/190/199us, ABANDONED ARM): sort-free LDS-atomic aggregation.
//   Lessons: (a) 12.8M cross-XCD global atomics = 100MB write traffic, never;
//   (b) LDS-float-atomic agg over bucket-sorted records = 47-50us/kernel,
//   INSENSITIVE to guard style, load batching, sched_barrier -> instruction
//   scheduling is not the lever; (c) cleanest surviving signal: k_hist
//   (512x256 blocks) streams 12.8MB + LDS atomics in ~8us while k_deg
//   (391x1024 blocks) takes ~30us for the same volume/atomic density.
// R15: restore R11 verbatim + ONE delta: k_bsort at 256 threads (was 1024),
//   same 391 blocks/LDS layout, 4x records per thread. Tests the
//   "1024-thread bucket-blocks are the poison" hypothesis on the kernel
//   where geometry is free to change. Predict bsort ~28 -> ~12-15us.

#define BLK 256
#define NTILE 512
#define EPTMAX 6400        // >= runtime ept (6252), multiple of 4
#define MAXB 512           // >= nbkt = 391

// ---------- Phase A (R11 verbatim) ----------

__global__ void k_hist(const int* __restrict__ dst, int* __restrict__ table,
                       int e, int ept, int nbkt) {
    __shared__ int h[MAXB];
    int tile = blockIdx.x;
    for (int i = threadIdx.x; i < MAXB; i += BLK) h[i] = 0;
    __syncthreads();
    int lo = tile * ept;
    int hi = min(lo + ept, e);
    for (int i = lo + 4 * threadIdx.x; i < hi; i += 4 * BLK) {
        int4 d4 = *(const int4*)(dst + i);
        atomicAdd(&h[d4.x >> 8], 1);
        atomicAdd(&h[d4.y >> 8], 1);
        atomicAdd(&h[d4.z >> 8], 1);
        atomicAdd(&h[d4.w >> 8], 1);
    }
    __syncthreads();
    for (int i = threadIdx.x; i < nbkt; i += BLK)
        table[tile * nbkt + i] = h[i];
}

__global__ void k_scan_col(int* __restrict__ table, int* __restrict__ tot, int nbkt) {
    __shared__ int wsum[NTILE / 64];
    int b = blockIdx.x;
    int t = threadIdx.x;
    int v = table[t * nbkt + b];
    int x = v;
    int lane = t & 63;
#pragma unroll
    for (int ofs = 1; ofs < 64; ofs <<= 1) {
        int y = __shfl_up(x, ofs, 64);
        if (lane >= ofs) x += y;
    }
    if (lane == 63) wsum[t >> 6] = x;
    __syncthreads();
    if (t < NTILE / 64) {
        int s = wsum[t];
        int w = s;
#pragma unroll
        for (int ofs = 1; ofs < NTILE / 64; ofs <<= 1) {
            int y = __shfl_up(w, ofs, 64);
            if (t >= ofs) w += y;
        }
        wsum[t] = w - s;
    }
    __syncthreads();
    int incl = x + wsum[t >> 6];
    table[t * nbkt + b] = incl - v;
    if (t == NTILE - 1) tot[b] = incl;
}

__global__ void k_scan_tot(const int* __restrict__ tot, int* __restrict__ bkt_off, int nbkt) {
    __shared__ int wsum[MAXB / 64];
    int t = threadIdx.x;               // MAXB threads
    int v = (t < nbkt) ? tot[t] : 0;
    int x = v;
    int lane = t & 63;
#pragma unroll
    for (int ofs = 1; ofs < 64; ofs <<= 1) {
        int y = __shfl_up(x, ofs, 64);
        if (lane >= ofs) x += y;
    }
    if (lane == 63) wsum[t >> 6] = x;
    __syncthreads();
    if (t < MAXB / 64) {
        int s = wsum[t];
        int w = s;
#pragma unroll
        for (int ofs = 1; ofs < MAXB / 64; ofs <<= 1) {
            int y = __shfl_up(w, ofs, 64);
            if (t >= ofs) w += y;
        }
        wsum[t] = w - s;
    }
    __syncthreads();
    int incl = x + wsum[t >> 6];
    if (t < nbkt) bkt_off[t] = incl - v;
    if (t == nbkt - 1) bkt_off[nbkt] = incl;
}

__global__ void k_scatter(const int* __restrict__ src, const int* __restrict__ dst,
                          const int* __restrict__ table, const int* __restrict__ tot,
                          const int* __restrict__ bkt_off, unsigned* __restrict__ sorted,
                          int e, int ept, int nbkt) {
    __shared__ int cur[MAXB];
    __shared__ int base2[MAXB];
    __shared__ unsigned stage[EPTMAX];
    __shared__ unsigned short stage_b[EPTMAX];
    __shared__ int wpart[BLK / 64];
    int tile = blockIdx.x;
    int t = threadIdx.x;
    int lo = tile * ept;
    int hi = min(lo + ept, e);
    int total = hi - lo;

    int b0 = 2 * t, b1 = 2 * t + 1;
    int c0 = 0, c1 = 0, g0 = 0, g1 = 0;
    if (b0 < nbkt) {
        int base = table[tile * nbkt + b0];
        int next = (tile < NTILE - 1) ? table[(tile + 1) * nbkt + b0] : tot[b0];
        c0 = next - base;
        g0 = bkt_off[b0] + base;
    }
    if (b1 < nbkt) {
        int base = table[tile * nbkt + b1];
        int next = (tile < NTILE - 1) ? table[(tile + 1) * nbkt + b1] : tot[b1];
        c1 = next - base;
        g1 = bkt_off[b1] + base;
    }
    int p = c0 + c1;
    int x = p;
    int lane = t & 63;
#pragma unroll
    for (int ofs = 1; ofs < 64; ofs <<= 1) {
        int y = __shfl_up(x, ofs, 64);
        if (lane >= ofs) x += y;
    }
    if (lane == 63) wpart[t >> 6] = x;
    __syncthreads();
    if (t < BLK / 64) {
        int s = wpart[t];
        int w = s;
#pragma unroll
        for (int ofs = 1; ofs < BLK / 64; ofs <<= 1) {
            int y = __shfl_up(w, ofs, 64);
            if (t >= ofs) w += y;
        }
        wpart[t] = w - s;
    }
    __syncthreads();
    int E = x + wpart[t >> 6] - p;
    cur[b0] = E;
    cur[b1] = E + c0;
    if (b0 < nbkt) base2[b0] = g0 - E;
    if (b1 < nbkt) base2[b1] = g1 - (E + c0);
    __syncthreads();

    for (int i = lo + 4 * t; i < hi; i += 4 * BLK) {
        int4 s4 = *(const int4*)(src + i);
        int4 d4 = *(const int4*)(dst + i);
        int b, pos;
        b = d4.x >> 8; pos = atomicAdd(&cur[b], 1);
        stage[pos] = (unsigned)s4.x | ((unsigned)(d4.x & 255) << 17); stage_b[pos] = (unsigned short)b;
        b = d4.y >> 8; pos = atomicAdd(&cur[b], 1);
        stage[pos] = (unsigned)s4.y | ((unsigned)(d4.y & 255) << 17); stage_b[pos] = (unsigned short)b;
        b = d4.z >> 8; pos = atomicAdd(&cur[b], 1);
        stage[pos] = (unsigned)s4.z | ((unsigned)(d4.z & 255) << 17); stage_b[pos] = (unsigned short)b;
        b = d4.w >> 8; pos = atomicAdd(&cur[b], 1);
        stage[pos] = (unsigned)s4.w | ((unsigned)(d4.w & 255) << 17); stage_b[pos] = (unsigned short)b;
    }
    __syncthreads();
    for (int j = t; j < total; j += BLK) {
        int b = stage_b[j];
        sorted[base2[b] + j] = stage[j];
    }
}

// ---------- per-bucket node-sort + degree + dinv + xp ----------
// R15 delta: 256 threads (was 1024). Same 391 blocks, same LDS histograms,
// each thread covers 4x the records.
__global__ __launch_bounds__(256) void k_bsort(
        const unsigned* __restrict__ sorted, const int* __restrict__ bkt_off,
        const float* __restrict__ x, float* __restrict__ dinv,
        float* __restrict__ xp, unsigned* __restrict__ nsorted,
        int* __restrict__ nodeoff, int n) {
    __shared__ int cnt[256];
    __shared__ int cur[256];
    __shared__ int wsum[4];
    int b = blockIdx.x, t = threadIdx.x;   // t in [0,256)
    cnt[t] = 0;
    __syncthreads();
    int lo = bkt_off[b], hi = bkt_off[b + 1];
    int la = lo & ~3;
    for (int i = la + 4 * t; i < hi; i += 4 * 256) {
        uint4 r = *(const uint4*)(sorted + i);   // aligned; pad covers overread
        if (i >= lo && i + 4 <= hi) {
            atomicAdd(&cnt[r.x >> 17], 1);
            atomicAdd(&cnt[r.y >> 17], 1);
            atomicAdd(&cnt[r.z >> 17], 1);
            atomicAdd(&cnt[r.w >> 17], 1);
        } else {
            if (i + 0 >= lo && i + 0 < hi) atomicAdd(&cnt[r.x >> 17], 1);
            if (i + 1 >= lo && i + 1 < hi) atomicAdd(&cnt[r.y >> 17], 1);
            if (i + 2 >= lo && i + 2 < hi) atomicAdd(&cnt[r.z >> 17], 1);
            if (i + 3 >= lo && i + 3 < hi) atomicAdd(&cnt[r.w >> 17], 1);
        }
    }
    __syncthreads();
    int c = cnt[t];
    int node = (b << 8) + t;
    if (node < n) {
        float d = rsqrtf((float)c + 1.0f);   // +1 self loop
        dinv[node] = d;
        float2 xv = ((const float2*)x)[node];
        ((float2*)xp)[node] = make_float2(d * xv.x, d * xv.y);
    }
    int xsc = c;
    int lane = t & 63;
#pragma unroll
    for (int ofs = 1; ofs < 64; ofs <<= 1) {
        int y = __shfl_up(xsc, ofs, 64);
        if (lane >= ofs) xsc += y;
    }
    if (lane == 63) wsum[t >> 6] = xsc;
    __syncthreads();
    if (t < 4) {
        int s = wsum[t];
        int w = s;
#pragma unroll
        for (int ofs = 1; ofs < 4; ofs <<= 1) {
            int y = __shfl_up(w, ofs, 64);
            if (t >= ofs) w += y;
        }
        wsum[t] = w - s;
    }
    __syncthreads();
    {
        int excl = xsc + wsum[t >> 6] - c;
        cur[t] = excl;
        nodeoff[(b << 8) + t] = lo + excl;
    }
    __syncthreads();
    for (int i = la + 4 * t; i < hi; i += 4 * 256) {
        uint4 r = *(const uint4*)(sorted + i);
        if (i >= lo && i + 4 <= hi) {
            int p0 = atomicAdd(&cur[r.x >> 17], 1); nsorted[lo + p0] = r.x & 0x1FFFFu;
            int p1 = atomicAdd(&cur[r.y >> 17], 1); nsorted[lo + p1] = r.y & 0x1FFFFu;
            int p2 = atomicAdd(&cur[r.z >> 17], 1); nsorted[lo + p2] = r.z & 0x1FFFFu;
            int p3 = atomicAdd(&cur[r.w >> 17], 1); nsorted[lo + p3] = r.w & 0x1FFFFu;
        } else {
            if (i + 0 >= lo && i + 0 < hi) { int p0 = atomicAdd(&cur[r.x >> 17], 1); nsorted[lo + p0] = r.x & 0x1FFFFu; }
            if (i + 1 >= lo && i + 1 < hi) { int p1 = atomicAdd(&cur[r.y >> 17], 1); nsorted[lo + p1] = r.y & 0x1FFFFu; }
            if (i + 2 >= lo && i + 2 < hi) { int p2 = atomicAdd(&cur[r.z >> 17], 1); nsorted[lo + p2] = r.z & 0x1FFFFu; }
            if (i + 3 >= lo && i + 3 < hi) { int p3 = atomicAdd(&cur[r.w >> 17], 1); nsorted[lo + p3] = r.w & 0x1FFFFu; }
        }
    }
}

// ---------- Phase B (R11 verbatim): segmented sums, aligned uint4 loads ----------

// layer 1 + fused MLP: gp[d] = dinv[d]*(relu(aggx@W1+b1)@W2)
__global__ void k_agg1(const unsigned* __restrict__ nsorted, const int* __restrict__ nodeoff,
                       const float* __restrict__ xp, const float* __restrict__ dinv,
                       const float* __restrict__ W1, const float* __restrict__ b1,
                       const float* __restrict__ W2, float* __restrict__ gp, int n) {
    int t = threadIdx.x;
    int nd = (blockIdx.x << 8) + (blockIdx.y << 6) + (t >> 2);
    int q = t & 3;
    if (nd >= n) return;
    int start = nodeoff[nd], end = nodeoff[nd + 1];
    const float2* xp2 = (const float2*)xp;
    float sx = 0.f, sy = 0.f;
    for (int p = (start & ~3) + 4 * q; p < end; p += 16) {
        uint4 r = *(const uint4*)(nsorted + p);   // aligned; pad covers overread
        if (p >= start && p + 4 <= end) {
            float2 f0 = xp2[r.x], f1 = xp2[r.y], f2 = xp2[r.z], f3 = xp2[r.w];
            sx += (f0.x + f1.x) + (f2.x + f3.x);
            sy += (f0.y + f1.y) + (f2.y + f3.y);
        } else {
            if (p + 0 >= start && p + 0 < end) { float2 f = xp2[r.x]; sx += f.x; sy += f.y; }
            if (p + 1 >= start && p + 1 < end) { float2 f = xp2[r.y]; sx += f.x; sy += f.y; }
            if (p + 2 >= start && p + 2 < end) { float2 f = xp2[r.z]; sx += f.x; sy += f.y; }
            if (p + 3 >= start && p + 3 < end) { float2 f = xp2[r.w]; sx += f.x; sy += f.y; }
        }
    }
    sx += __shfl_xor(sx, 1); sy += __shfl_xor(sy, 1);
    sx += __shfl_xor(sx, 2); sy += __shfl_xor(sy, 2);
    if (q == 0) {
        float d = dinv[nd];
        float2 xv = xp2[nd];
        float ax = d * (sx + xv.x), ay = d * (sy + xv.y);
        float g0 = 0.f, g1 = 0.f;
#pragma unroll
        for (int f = 0; f < 16; ++f) {
            float h = fmaf(ax, W1[f], fmaf(ay, W1[16 + f], b1[f]));
            h = fmaxf(h, 0.0f);
            g0 = fmaf(h, W2[2 * f + 0], g0);
            g1 = fmaf(h, W2[2 * f + 1], g1);
        }
        ((float2*)gp)[nd] = make_float2(d * g0, d * g1);
    }
}

// layer 2 + bias + log_softmax
__global__ void k_agg2(const unsigned* __restrict__ nsorted, const int* __restrict__ nodeoff,
                       const float* __restrict__ gp, const float* __restrict__ dinv,
                       const float* __restrict__ b2, float* __restrict__ out, int n) {
    int t = threadIdx.x;
    int nd = (blockIdx.x << 8) + (blockIdx.y << 6) + (t >> 2);
    int q = t & 3;
    if (nd >= n) return;
    int start = nodeoff[nd], end = nodeoff[nd + 1];
    const float2* gp2 = (const float2*)gp;
    float sx = 0.f, sy = 0.f;
    for (int p = (start & ~3) + 4 * q; p < end; p += 16) {
        uint4 r = *(const uint4*)(nsorted + p);
        if (p >= start && p + 4 <= end) {
            float2 f0 = gp2[r.x], f1 = gp2[r.y], f2 = gp2[r.z], f3 = gp2[r.w];
            sx += (f0.x + f1.x) + (f2.x + f3.x);
            sy += (f0.y + f1.y) + (f2.y + f3.y);
        } else {
            if (p + 0 >= start && p + 0 < end) { float2 f = gp2[r.x]; sx += f.x; sy += f.y; }
            if (p + 1 >= start && p + 1 < end) { float2 f = gp2[r.y]; sx += f.x; sy += f.y; }
            if (p + 2 >= start && p + 2 < end) { float2 f = gp2[r.z]; sx += f.x; sy += f.y; }
            if (p + 3 >= start && p + 3 < end) { float2 f = gp2[r.w]; sx += f.x; sy += f.y; }
        }
    }
    sx += __shfl_xor(sx, 1); sy += __shfl_xor(sy, 1);
    sx += __shfl_xor(sx, 2); sy += __shfl_xor(sy, 2);
    if (q == 0) {
        float d = dinv[nd];
        float2 gv = gp2[nd];
        float z0 = d * (sx + gv.x) + b2[0];
        float z1 = d * (sy + gv.y) + b2[1];
        float m = fmaxf(z0, z1);
        float lse = m + logf(expf(z0 - m) + expf(z1 - m));
        ((float2*)out)[nd] = make_float2(z0 - lse, z1 - lse);
    }
}

extern "C" void kernel_launch(void* const* d_in, const int* in_sizes, int n_in,
                              void* d_out, int out_size, void* d_ws, size_t ws_size,
                              hipStream_t stream) {
    const float* x  = (const float*)d_in[0];   // [n,2]
    const int*   ei = (const int*)d_in[1];     // [2,e]: row0=src, row1=dst
    const float* W1 = (const float*)d_in[2];   // [2,16]
    const float* b1 = (const float*)d_in[3];   // [16]
    const float* W2 = (const float*)d_in[4];   // [16,2]
    const float* b2 = (const float*)d_in[5];   // [2]
    float* out = (float*)d_out;                // [n,2]

    const int n = in_sizes[0] / 2;             // 100000
    const int e = in_sizes[1] / 2;             // 3200000
    const int* src = ei;
    const int* dst = ei + e;

    const int nbkt = (n + 255) >> 8;           // 391
    int ept = (((e + NTILE - 1) / NTILE) + 3) & ~3;   // 6252

    char* base = (char*)d_ws;
    size_t off = 0;
    auto take = [&](size_t bytes) { char* p = base + off; off += (bytes + 255) & ~(size_t)255; return p; };
    unsigned* sorted  = (unsigned*)take(((size_t)e + 8) * 4);             // 12.8 MB (+pad)
    int*      table   = (int*)take((size_t)NTILE * nbkt * 4);             // 0.8 MB
    int*      tot     = (int*)take((size_t)MAXB * 4);
    int*      bkt_off = (int*)take((size_t)(MAXB + 1) * 4);
    unsigned* nsorted = (unsigned*)take(((size_t)e + 8) * 4);             // 12.8 MB (+pad)
    int*      nodeoff = (int*)take((size_t)(nbkt * 256 + 64) * 4);        // 0.4 MB
    float*    dinv    = (float*)take((size_t)n * 4);
    float*    xp      = (float*)take((size_t)n * 8);
    float*    gp      = (float*)take((size_t)n * 8);

    dim3 gagg(nbkt, 4);

    k_hist    <<<NTILE, BLK, 0, stream>>>(dst, table, e, ept, nbkt);
    k_scan_col<<<nbkt, NTILE, 0, stream>>>(table, tot, nbkt);
    k_scan_tot<<<1, MAXB, 0, stream>>>(tot, bkt_off, nbkt);
    k_scatter <<<NTILE, BLK, 0, stream>>>(src, dst, table, tot, bkt_off, sorted, e, ept, nbkt);
    k_bsort   <<<nbkt, 256, 0, stream>>>(sorted, bkt_off, x, dinv, xp, nsorted, nodeoff, n);
    k_agg1    <<<gagg, BLK, 0, stream>>>(nsorted, nodeoff, xp, dinv, W1, b1, W2, gp, n);
    k_agg2    <<<gagg, BLK, 0, stream>>>(nsorted, nodeoff, gp, dinv, b2, out, n);
}

// Round 5
// 154.268 us; speedup vs baseline: 1.2908x; 1.0199x over previous
//
#include <hip/hip_runtime.h>
#include <math.h>

// GCN 2-layer, algebraically fused:
//   agg_x[d] = dinv[d]*(sum_{s in N(d)} xp[s] + xp[d]),  xp = dinv*x
//   h = relu(agg_x@W1+b1); g = h@W2; gp = dinv*g
//   out = log_softmax(dinv[d]*(sum gp[s] + gp[d]) + b2)
//
// R11 (157.1us): two-level counting sort -> node-contiguous records;
//   atomic-free segmented-sum aggregation; MLP fused into k_agg1.
// R12-R14 (315/190/199us, ABANDONED): sort-free LDS-float-atomic agg =
//   47-50us/kernel, insensitive to scheduling; global-atomic degree = 100MB
//   cross-XCD traffic. Lesson: register-sum agg is the fast pattern; LDS
//   int position-atomics (sort) are fine, LDS float accumulate is not.
// R15 (157.3us): R11 + 256-thread bsort — neutral; geometry not the lever.
// R16: split bsort at its sync point and fuse agg1 into the scatter half.
//   k_cnt  = count + dinv/xp + nodeoff (bsort pass 1).
//   k_sagg1= re-read sorted, LDS-atomic scatter to node order, mirror the
//            node-sorted records in LDS (srt[]) while writing nsorted for
//            agg2, then run agg1's 4-lane/node register sums straight from
//            LDS. Kills agg1's separate 12.8MB nsorted read + 1 launch +
//            the record-load->gather global 2-hop chain.
//   k_agg2 unchanged (R11 pattern over nsorted).
// Fixed ~43us of the measured total is harness workspace fill.

#define BLK 256
#define NTILE 512
#define EPTMAX 6400        // >= runtime ept (6252), multiple of 4
#define MAXB 512           // >= nbkt = 391
#define MSK 0x1FFFFu
#define SRTMAX 10240       // >= max bucket size (mean 8187, sigma ~90)

// ---------- Phase A (R11 verbatim) ----------

__global__ void k_hist(const int* __restrict__ dst, int* __restrict__ table,
                       int e, int ept, int nbkt) {
    __shared__ int h[MAXB];
    int tile = blockIdx.x;
    for (int i = threadIdx.x; i < MAXB; i += BLK) h[i] = 0;
    __syncthreads();
    int lo = tile * ept;
    int hi = min(lo + ept, e);
    for (int i = lo + 4 * threadIdx.x; i < hi; i += 4 * BLK) {
        int4 d4 = *(const int4*)(dst + i);
        atomicAdd(&h[d4.x >> 8], 1);
        atomicAdd(&h[d4.y >> 8], 1);
        atomicAdd(&h[d4.z >> 8], 1);
        atomicAdd(&h[d4.w >> 8], 1);
    }
    __syncthreads();
    for (int i = threadIdx.x; i < nbkt; i += BLK)
        table[tile * nbkt + i] = h[i];
}

__global__ void k_scan_col(int* __restrict__ table, int* __restrict__ tot, int nbkt) {
    __shared__ int wsum[NTILE / 64];
    int b = blockIdx.x;
    int t = threadIdx.x;
    int v = table[t * nbkt + b];
    int x = v;
    int lane = t & 63;
#pragma unroll
    for (int ofs = 1; ofs < 64; ofs <<= 1) {
        int y = __shfl_up(x, ofs, 64);
        if (lane >= ofs) x += y;
    }
    if (lane == 63) wsum[t >> 6] = x;
    __syncthreads();
    if (t < NTILE / 64) {
        int s = wsum[t];
        int w = s;
#pragma unroll
        for (int ofs = 1; ofs < NTILE / 64; ofs <<= 1) {
            int y = __shfl_up(w, ofs, 64);
            if (t >= ofs) w += y;
        }
        wsum[t] = w - s;
    }
    __syncthreads();
    int incl = x + wsum[t >> 6];
    table[t * nbkt + b] = incl - v;
    if (t == NTILE - 1) tot[b] = incl;
}

__global__ void k_scan_tot(const int* __restrict__ tot, int* __restrict__ bkt_off, int nbkt) {
    __shared__ int wsum[MAXB / 64];
    int t = threadIdx.x;               // MAXB threads
    int v = (t < nbkt) ? tot[t] : 0;
    int x = v;
    int lane = t & 63;
#pragma unroll
    for (int ofs = 1; ofs < 64; ofs <<= 1) {
        int y = __shfl_up(x, ofs, 64);
        if (lane >= ofs) x += y;
    }
    if (lane == 63) wsum[t >> 6] = x;
    __syncthreads();
    if (t < MAXB / 64) {
        int s = wsum[t];
        int w = s;
#pragma unroll
        for (int ofs = 1; ofs < MAXB / 64; ofs <<= 1) {
            int y = __shfl_up(w, ofs, 64);
            if (t >= ofs) w += y;
        }
        wsum[t] = w - s;
    }
    __syncthreads();
    int incl = x + wsum[t >> 6];
    if (t < nbkt) bkt_off[t] = incl - v;
    if (t == nbkt - 1) bkt_off[nbkt] = incl;
}

__global__ void k_scatter(const int* __restrict__ src, const int* __restrict__ dst,
                          const int* __restrict__ table, const int* __restrict__ tot,
                          const int* __restrict__ bkt_off, unsigned* __restrict__ sorted,
                          int e, int ept, int nbkt) {
    __shared__ int cur[MAXB];
    __shared__ int base2[MAXB];
    __shared__ unsigned stage[EPTMAX];
    __shared__ unsigned short stage_b[EPTMAX];
    __shared__ int wpart[BLK / 64];
    int tile = blockIdx.x;
    int t = threadIdx.x;
    int lo = tile * ept;
    int hi = min(lo + ept, e);
    int total = hi - lo;

    int b0 = 2 * t, b1 = 2 * t + 1;
    int c0 = 0, c1 = 0, g0 = 0, g1 = 0;
    if (b0 < nbkt) {
        int base = table[tile * nbkt + b0];
        int next = (tile < NTILE - 1) ? table[(tile + 1) * nbkt + b0] : tot[b0];
        c0 = next - base;
        g0 = bkt_off[b0] + base;
    }
    if (b1 < nbkt) {
        int base = table[tile * nbkt + b1];
        int next = (tile < NTILE - 1) ? table[(tile + 1) * nbkt + b1] : tot[b1];
        c1 = next - base;
        g1 = bkt_off[b1] + base;
    }
    int p = c0 + c1;
    int x = p;
    int lane = t & 63;
#pragma unroll
    for (int ofs = 1; ofs < 64; ofs <<= 1) {
        int y = __shfl_up(x, ofs, 64);
        if (lane >= ofs) x += y;
    }
    if (lane == 63) wpart[t >> 6] = x;
    __syncthreads();
    if (t < BLK / 64) {
        int s = wpart[t];
        int w = s;
#pragma unroll
        for (int ofs = 1; ofs < BLK / 64; ofs <<= 1) {
            int y = __shfl_up(w, ofs, 64);
            if (t >= ofs) w += y;
        }
        wpart[t] = w - s;
    }
    __syncthreads();
    int E = x + wpart[t >> 6] - p;
    cur[b0] = E;
    cur[b1] = E + c0;
    if (b0 < nbkt) base2[b0] = g0 - E;
    if (b1 < nbkt) base2[b1] = g1 - (E + c0);
    __syncthreads();

    for (int i = lo + 4 * t; i < hi; i += 4 * BLK) {
        int4 s4 = *(const int4*)(src + i);
        int4 d4 = *(const int4*)(dst + i);
        int b, pos;
        b = d4.x >> 8; pos = atomicAdd(&cur[b], 1);
        stage[pos] = (unsigned)s4.x | ((unsigned)(d4.x & 255) << 17); stage_b[pos] = (unsigned short)b;
        b = d4.y >> 8; pos = atomicAdd(&cur[b], 1);
        stage[pos] = (unsigned)s4.y | ((unsigned)(d4.y & 255) << 17); stage_b[pos] = (unsigned short)b;
        b = d4.z >> 8; pos = atomicAdd(&cur[b], 1);
        stage[pos] = (unsigned)s4.z | ((unsigned)(d4.z & 255) << 17); stage_b[pos] = (unsigned short)b;
        b = d4.w >> 8; pos = atomicAdd(&cur[b], 1);
        stage[pos] = (unsigned)s4.w | ((unsigned)(d4.w & 255) << 17); stage_b[pos] = (unsigned short)b;
    }
    __syncthreads();
    for (int j = t; j < total; j += BLK) {
        int b = stage_b[j];
        sorted[base2[b] + j] = stage[j];
    }
}

// ---------- k_cnt: per-bucket count + dinv + xp + nodeoff (bsort pass 1) ----------
__global__ __launch_bounds__(256) void k_cnt(
        const unsigned* __restrict__ sorted, const int* __restrict__ bkt_off,
        const float* __restrict__ x, float* __restrict__ dinv,
        float* __restrict__ xp, int* __restrict__ nodeoff, int n, int nbkt) {
    __shared__ int cnt[256];
    __shared__ int wsum[4];
    int b = blockIdx.x, t = threadIdx.x;   // t in [0,256)
    cnt[t] = 0;
    __syncthreads();
    int lo = bkt_off[b], hi = bkt_off[b + 1];
    int la = lo & ~3;
    for (int i = la + 4 * t; i < hi; i += 4 * 256) {
        uint4 r = *(const uint4*)(sorted + i);   // aligned; pad covers overread
        if (i >= lo && i + 4 <= hi) {
            atomicAdd(&cnt[r.x >> 17], 1);
            atomicAdd(&cnt[r.y >> 17], 1);
            atomicAdd(&cnt[r.z >> 17], 1);
            atomicAdd(&cnt[r.w >> 17], 1);
        } else {
            if (i + 0 >= lo && i + 0 < hi) atomicAdd(&cnt[r.x >> 17], 1);
            if (i + 1 >= lo && i + 1 < hi) atomicAdd(&cnt[r.y >> 17], 1);
            if (i + 2 >= lo && i + 2 < hi) atomicAdd(&cnt[r.z >> 17], 1);
            if (i + 3 >= lo && i + 3 < hi) atomicAdd(&cnt[r.w >> 17], 1);
        }
    }
    __syncthreads();
    int c = cnt[t];
    int node = (b << 8) + t;
    if (node < n) {
        float d = rsqrtf((float)c + 1.0f);   // +1 self loop
        dinv[node] = d;
        float2 xv = ((const float2*)x)[node];
        ((float2*)xp)[node] = make_float2(d * xv.x, d * xv.y);
    }
    int xsc = c;
    int lane = t & 63;
#pragma unroll
    for (int ofs = 1; ofs < 64; ofs <<= 1) {
        int y = __shfl_up(xsc, ofs, 64);
        if (lane >= ofs) xsc += y;
    }
    if (lane == 63) wsum[t >> 6] = xsc;
    __syncthreads();
    if (t < 4) {
        int s = wsum[t];
        int w = s;
#pragma unroll
        for (int ofs = 1; ofs < 4; ofs <<= 1) {
            int y = __shfl_up(w, ofs, 64);
            if (t >= ofs) w += y;
        }
        wsum[t] = w - s;
    }
    __syncthreads();
    int excl = xsc + wsum[t >> 6] - c;
    nodeoff[node] = lo + excl;
    if (b == nbkt - 1 && t == 255) nodeoff[node + 1] = hi;   // sentinel
}

// ---------- k_sagg1: node-order scatter (LDS-mirrored) + fused agg1+MLP ----------
// bsort pass 2 + agg1 in one kernel: records land in srt[] (LDS) in
// node-contiguous order AND in nsorted (global, for agg2); the 4-lane/node
// register sums then read records from LDS — no global record re-read.
__global__ __launch_bounds__(1024) void k_sagg1(
        const unsigned* __restrict__ sorted, const int* __restrict__ bkt_off,
        const int* __restrict__ nodeoff, const float* __restrict__ xp,
        const float* __restrict__ dinv, const float* __restrict__ W1,
        const float* __restrict__ b1, const float* __restrict__ W2,
        float* __restrict__ gp, unsigned* __restrict__ nsorted, int n) {
    __shared__ unsigned srt[SRTMAX];
    __shared__ int cur[256];
    __shared__ int stt[257];
    int b = blockIdx.x, t = threadIdx.x;
    int lo = bkt_off[b], hi = bkt_off[b + 1];
    if (t < 256) {
        int s = nodeoff[(b << 8) + t] - lo;
        cur[t] = s;
        stt[t] = s;
        if (t == 255) stt[256] = hi - lo;
    }
    __syncthreads();
    int la = lo & ~3;
    for (int i = la + 4 * t; i < hi; i += 4 * 1024) {
        uint4 r = *(const uint4*)(sorted + i);   // aligned; pad covers overread
        if (i >= lo && i + 4 <= hi) {
            int p0 = atomicAdd(&cur[r.x >> 17], 1); unsigned v0 = r.x & MSK; srt[p0] = v0; nsorted[lo + p0] = v0;
            int p1 = atomicAdd(&cur[r.y >> 17], 1); unsigned v1 = r.y & MSK; srt[p1] = v1; nsorted[lo + p1] = v1;
            int p2 = atomicAdd(&cur[r.z >> 17], 1); unsigned v2 = r.z & MSK; srt[p2] = v2; nsorted[lo + p2] = v2;
            int p3 = atomicAdd(&cur[r.w >> 17], 1); unsigned v3 = r.w & MSK; srt[p3] = v3; nsorted[lo + p3] = v3;
        } else {
            if (i + 0 >= lo && i + 0 < hi) { int p0 = atomicAdd(&cur[r.x >> 17], 1); unsigned v0 = r.x & MSK; srt[p0] = v0; nsorted[lo + p0] = v0; }
            if (i + 1 >= lo && i + 1 < hi) { int p1 = atomicAdd(&cur[r.y >> 17], 1); unsigned v1 = r.y & MSK; srt[p1] = v1; nsorted[lo + p1] = v1; }
            if (i + 2 >= lo && i + 2 < hi) { int p2 = atomicAdd(&cur[r.z >> 17], 1); unsigned v2 = r.z & MSK; srt[p2] = v2; nsorted[lo + p2] = v2; }
            if (i + 3 >= lo && i + 3 < hi) { int p3 = atomicAdd(&cur[r.w >> 17], 1); unsigned v3 = r.w & MSK; srt[p3] = v3; nsorted[lo + p3] = v3; }
        }
    }
    __syncthreads();

    // agg1: 4 lanes/node over LDS-resident node-contiguous records
    int nl = t >> 2, q = t & 3;
    int gid = (b << 8) + nl;
    int s = stt[nl], epos = stt[nl + 1];
    const float2* xp2 = (const float2*)xp;
    float sx = 0.f, sy = 0.f;
    for (int p = s + q; p < epos; p += 4) {
        float2 f = xp2[srt[p]];
        sx += f.x; sy += f.y;
    }
    sx += __shfl_xor(sx, 1); sy += __shfl_xor(sy, 1);
    sx += __shfl_xor(sx, 2); sy += __shfl_xor(sy, 2);
    if (q == 0 && gid < n) {
        float d = dinv[gid];
        float2 xv = xp2[gid];
        float ax = d * (sx + xv.x), ay = d * (sy + xv.y);
        float g0 = 0.f, g1 = 0.f;
#pragma unroll
        for (int f = 0; f < 16; ++f) {
            float h = fmaf(ax, W1[f], fmaf(ay, W1[16 + f], b1[f]));
            h = fmaxf(h, 0.0f);
            g0 = fmaf(h, W2[2 * f + 0], g0);
            g1 = fmaf(h, W2[2 * f + 1], g1);
        }
        ((float2*)gp)[gid] = make_float2(d * g0, d * g1);
    }
}

// ---------- layer 2 + bias + log_softmax (R11 verbatim) ----------
__global__ void k_agg2(const unsigned* __restrict__ nsorted, const int* __restrict__ nodeoff,
                       const float* __restrict__ gp, const float* __restrict__ dinv,
                       const float* __restrict__ b2, float* __restrict__ out, int n) {
    int t = threadIdx.x;
    int nd = (blockIdx.x << 8) + (blockIdx.y << 6) + (t >> 2);
    int q = t & 3;
    if (nd >= n) return;
    int start = nodeoff[nd], end = nodeoff[nd + 1];
    const float2* gp2 = (const float2*)gp;
    float sx = 0.f, sy = 0.f;
    for (int p = (start & ~3) + 4 * q; p < end; p += 16) {
        uint4 r = *(const uint4*)(nsorted + p);
        if (p >= start && p + 4 <= end) {
            float2 f0 = gp2[r.x], f1 = gp2[r.y], f2 = gp2[r.z], f3 = gp2[r.w];
            sx += (f0.x + f1.x) + (f2.x + f3.x);
            sy += (f0.y + f1.y) + (f2.y + f3.y);
        } else {
            if (p + 0 >= start && p + 0 < end) { float2 f = gp2[r.x]; sx += f.x; sy += f.y; }
            if (p + 1 >= start && p + 1 < end) { float2 f = gp2[r.y]; sx += f.x; sy += f.y; }
            if (p + 2 >= start && p + 2 < end) { float2 f = gp2[r.z]; sx += f.x; sy += f.y; }
            if (p + 3 >= start && p + 3 < end) { float2 f = gp2[r.w]; sx += f.x; sy += f.y; }
        }
    }
    sx += __shfl_xor(sx, 1); sy += __shfl_xor(sy, 1);
    sx += __shfl_xor(sx, 2); sy += __shfl_xor(sy, 2);
    if (q == 0) {
        float d = dinv[nd];
        float2 gv = gp2[nd];
        float z0 = d * (sx + gv.x) + b2[0];
        float z1 = d * (sy + gv.y) + b2[1];
        float m = fmaxf(z0, z1);
        float lse = m + logf(expf(z0 - m) + expf(z1 - m));
        ((float2*)out)[nd] = make_float2(z0 - lse, z1 - lse);
    }
}

extern "C" void kernel_launch(void* const* d_in, const int* in_sizes, int n_in,
                              void* d_out, int out_size, void* d_ws, size_t ws_size,
                              hipStream_t stream) {
    const float* x  = (const float*)d_in[0];   // [n,2]
    const int*   ei = (const int*)d_in[1];     // [2,e]: row0=src, row1=dst
    const float* W1 = (const float*)d_in[2];   // [2,16]
    const float* b1 = (const float*)d_in[3];   // [16]
    const float* W2 = (const float*)d_in[4];   // [16,2]
    const float* b2 = (const float*)d_in[5];   // [2]
    float* out = (float*)d_out;                // [n,2]

    const int n = in_sizes[0] / 2;             // 100000
    const int e = in_sizes[1] / 2;             // 3200000
    const int* src = ei;
    const int* dst = ei + e;

    const int nbkt = (n + 255) >> 8;           // 391
    int ept = (((e + NTILE - 1) / NTILE) + 3) & ~3;   // 6252

    char* base = (char*)d_ws;
    size_t off = 0;
    auto take = [&](size_t bytes) { char* p = base + off; off += (bytes + 255) & ~(size_t)255; return p; };
    unsigned* sorted  = (unsigned*)take(((size_t)e + 8) * 4);             // 12.8 MB (+pad)
    int*      table   = (int*)take((size_t)NTILE * nbkt * 4);             // 0.8 MB
    int*      tot     = (int*)take((size_t)MAXB * 4);
    int*      bkt_off = (int*)take((size_t)(MAXB + 1) * 4);
    unsigned* nsorted = (unsigned*)take(((size_t)e + 8) * 4);             // 12.8 MB (+pad)
    int*      nodeoff = (int*)take((size_t)(nbkt * 256 + 64) * 4);        // 0.4 MB
    float*    dinv    = (float*)take((size_t)n * 4);
    float*    xp      = (float*)take((size_t)n * 8);
    float*    gp      = (float*)take((size_t)n * 8);

    dim3 gagg(nbkt, 4);

    k_hist    <<<NTILE, BLK, 0, stream>>>(dst, table, e, ept, nbkt);
    k_scan_col<<<nbkt, NTILE, 0, stream>>>(table, tot, nbkt);
    k_scan_tot<<<1, MAXB, 0, stream>>>(tot, bkt_off, nbkt);
    k_scatter <<<NTILE, BLK, 0, stream>>>(src, dst, table, tot, bkt_off, sorted, e, ept, nbkt);
    k_cnt     <<<nbkt, 256, 0, stream>>>(sorted, bkt_off, x, dinv, xp, nodeoff, n, nbkt);
    k_sagg1   <<<nbkt, 1024, 0, stream>>>(sorted, bkt_off, nodeoff, xp, dinv, W1, b1, W2, gp, nsorted, n);
    k_agg2    <<<gagg, BLK, 0, stream>>>(nsorted, nodeoff, gp, dinv, b2, out, n);
}